// Round 1
// baseline (417.511 us; speedup 1.0000x reference)
//
#include <hip/hip_runtime.h>

#define N 8192
#define F 128
#define ALPHA 0.2f
#define NSPLIT 4

typedef __attribute__((ext_vector_type(8))) short short8;
typedef __attribute__((ext_vector_type(4))) float f32x4;
typedef unsigned short u16;

__device__ __forceinline__ u16 f2bf(float f) {
    unsigned int u = __float_as_uint(f);
    u += 0x7fff + ((u >> 16) & 1);  // RNE; inputs are finite, no NaN handling needed
    return (u16)(u >> 16);
}

// ---------------- K1: h = x@W ; emit hT (bf16, [feature][node]) + ssrc/sdst (fp32) ----------------
__global__ __launch_bounds__(256) void gemm_h(const float* __restrict__ x,
                                              const float* __restrict__ W,
                                              const float* __restrict__ aa,
                                              u16* __restrict__ hT,
                                              float* __restrict__ ssrc,
                                              float* __restrict__ sdst) {
    __shared__ float xs[32 * 128];
    __shared__ float Wsh[32 * 128];
    const int t = threadIdx.x;
    const int i0 = blockIdx.x * 32;
    const int c4 = (t & 31) * 4;
    const int r8 = t >> 5;

#pragma unroll
    for (int p = 0; p < 4; ++p) {
        int rr = p * 8 + r8;
        *(float4*)&xs[rr * 128 + c4] = *(const float4*)&x[(size_t)(i0 + rr) * 128 + c4];
    }

    const int tx = t & 31, ty = t >> 5;
    const int r0 = ty * 4, c0 = tx * 4;
    float acc[4][4] = {};

    for (int kc = 0; kc < 4; ++kc) {
        __syncthreads();
#pragma unroll
        for (int p = 0; p < 4; ++p) {
            int k = p * 8 + r8;
            *(float4*)&Wsh[k * 128 + c4] = *(const float4*)&W[(kc * 32 + k) * 128 + c4];
        }
        __syncthreads();
#pragma unroll 4
        for (int k = 0; k < 32; k += 4) {
            float xr[4][4];
#pragma unroll
            for (int rr = 0; rr < 4; ++rr)
                *(float4*)xr[rr] = *(const float4*)&xs[(r0 + rr) * 128 + kc * 32 + k];
#pragma unroll
            for (int kk = 0; kk < 4; ++kk) {
                float4 wv = *(const float4*)&Wsh[(k + kk) * 128 + c0];
#pragma unroll
                for (int rr = 0; rr < 4; ++rr) {
                    acc[rr][0] += xr[rr][kk] * wv.x;
                    acc[rr][1] += xr[rr][kk] * wv.y;
                    acc[rr][2] += xr[rr][kk] * wv.z;
                    acc[rr][3] += xr[rr][kk] * wv.w;
                }
            }
        }
    }

    // epilogue 1: hT bf16 transposed store
#pragma unroll
    for (int rr = 0; rr < 4; ++rr)
#pragma unroll
        for (int cc = 0; cc < 4; ++cc)
            hT[(size_t)(c0 + cc) * N + (i0 + r0 + rr)] = f2bf(acc[rr][cc]);

    // epilogue 2: fused scores s_src/s_dst from full-precision accumulators
    float4 asv = *(const float4*)&aa[c0];
    float4 adv = *(const float4*)&aa[F + c0];
#pragma unroll
    for (int rr = 0; rr < 4; ++rr) {
        float vs = acc[rr][0] * asv.x + acc[rr][1] * asv.y + acc[rr][2] * asv.z + acc[rr][3] * asv.w;
        float vd = acc[rr][0] * adv.x + acc[rr][1] * adv.y + acc[rr][2] * adv.z + acc[rr][3] * adv.w;
#pragma unroll
        for (int off = 16; off >= 1; off >>= 1) {
            vs += __shfl_down(vs, off, 32);
            vd += __shfl_down(vd, off, 32);
        }
        if (tx == 0) {
            ssrc[i0 + r0 + rr] = vs;
            sdst[i0 + r0 + rr] = vd;
        }
    }
}

// ---------------- K2: attention via bf16 MFMA ----------------
// Block: 32 i-rows, 4 waves, 1/NSPLIT of the j-range. Wave w produces A-frag-set
// (rt=w&1, ks=w>>1) from adj in-lane, consumes all 4 frag-sets for features [w*32,w*32+32).
// Depth-2 register pipeline on adj (HBM), depth-1 on sdst/B (L2-resident).
__global__ __launch_bounds__(256, 3) void attn_mfma(const int* __restrict__ adj,
                                                    const u16* __restrict__ hT,
                                                    const float* __restrict__ ssrc,
                                                    const float* __restrict__ sdst,
                                                    float* __restrict__ out,
                                                    float* __restrict__ pacc,
                                                    float* __restrict__ pS) {
    __shared__ short8 wsh[2][4][64];   // 8 KB: [buf][frag-set rt*2+ks][lane]
    __shared__ float srow[2][2][16];

    const int t = threadIdx.x;
    const int w = t >> 6, L = t & 63;
    const int quad = L >> 4, l16 = L & 15;
    const int i0 = blockIdx.x * 32;
    const int split = blockIdx.y;
    const int JW = N / NSPLIT;          // 2048
    const int jbase = split * JW;
    const int NC = JW / 64;             // 32 chunks

    const int rt = w & 1, ks = w >> 1;
    const int fragid = rt * 2 + ks;
    const int prow = i0 + rt * 16 + l16;
    const float s_i = ssrc[prow];

    const int* pA = adj + (size_t)prow * N + jbase + ks * 32 + quad * 8;
    const float* pD = sdst + jbase + ks * 32 + quad * 8;
    const u16* pB = hT + (size_t)(w * 32 + l16) * N + jbase + quad * 8;

    f32x4 acc[2][2];
#pragma unroll
    for (int a = 0; a < 2; ++a)
#pragma unroll
        for (int b = 0; b < 2; ++b) acc[a][b] = 0.f;
    float rsum = 0.f;

    // 8 w values -> bf16 frag (v_cvt_pk_bf16_f32, RNE == f2bf) + exact bf16 rowsum
    auto compute_write = [&](int buf, int4 a0, int4 a1, float4 d0, float4 d1) {
        const int m[8] = {a0.x, a0.y, a0.z, a0.w, a1.x, a1.y, a1.z, a1.w};
        const float d[8] = {d0.x, d0.y, d0.z, d0.w, d1.x, d1.y, d1.z, d1.w};
        float wv[8];
#pragma unroll
        for (int k = 0; k < 8; ++k) {
            float z = s_i + d[k];
            float e = __expf(fmaxf(z, ALPHA * z));
            wv[k] = (m[k] > 0) ? e : 0.f;
        }
        union { unsigned int u[4]; short8 s8; } pk;
        float s = 0.f;
#pragma unroll
        for (int p = 0; p < 4; ++p) {
            unsigned int r;
            asm("v_cvt_pk_bf16_f32 %0, %1, %2" : "=v"(r) : "v"(wv[2 * p]), "v"(wv[2 * p + 1]));
            pk.u[p] = r;
            s += __uint_as_float(r << 16);          // bf2f(element 2p)
            s += __uint_as_float(r & 0xffff0000u);  // bf2f(element 2p+1)
        }
        rsum += s;
        wsh[buf][fragid][L] = pk.s8;
    };

    // ---- prologue: chunks 0..2 into the pipeline ----
    int4 aN0 = *(const int4*)(pA);
    int4 aN1 = *(const int4*)(pA + 4);
    int4 aP0 = *(const int4*)(pA + 64);
    int4 aP1 = *(const int4*)(pA + 68);
    float4 dN0 = *(const float4*)(pD);
    float4 dN1 = *(const float4*)(pD + 4);
    compute_write(0, aN0, aN1, dN0, dN1);
    aN0 = aP0; aN1 = aP1;                       // chunk 1 -> current
    aP0 = *(const int4*)(pA + 128);             // chunk 2 in flight
    aP1 = *(const int4*)(pA + 132);
    dN0 = *(const float4*)(pD + 64);            // sdst chunk 1
    dN1 = *(const float4*)(pD + 68);

    short8 Bbuf[2][2];
#pragma unroll
    for (int c2 = 0; c2 < 2; ++c2)
#pragma unroll
        for (int kb = 0; kb < 2; ++kb)
            Bbuf[c2][kb] = *(const short8*)(pB + (size_t)c2 * 16 * N + kb * 32);

    for (int c = 1; c < NC; ++c) {
        __syncthreads();  // wsh[(c-1)&1] ready; buf (c&1) readers (chunk c-2) long done
        const int coff = c * 64;

        // B(c) in flight across this iteration (consumed next iter / epilogue)
        short8 Bload[2][2];
#pragma unroll
        for (int c2 = 0; c2 < 2; ++c2)
#pragma unroll
            for (int kb = 0; kb < 2; ++kb)
                Bload[c2][kb] = *(const short8*)(pB + (size_t)c2 * 16 * N + kb * 32 + coff);

        // w(c): adj regs were issued 2 iterations ago, sdst 1 iteration ago
        compute_write(c & 1, aN0, aN1, dN0, dN1);

        // rotate; prefetch adj chunk c+2 (2-iter distance), sdst chunk c+1
        aN0 = aP0; aN1 = aP1;
        const int ca = (c + 2 < NC) ? c + 2 : NC - 1;   // clamped redundant tail load: harmless
        aP0 = *(const int4*)(pA + ca * 64);
        aP1 = *(const int4*)(pA + ca * 64 + 4);
        const int cd = (c + 1 < NC) ? c + 1 : NC - 1;
        dN0 = *(const float4*)(pD + cd * 64);
        dN1 = *(const float4*)(pD + cd * 64 + 4);

        // MFMA chunk c-1
        short8 af[4];
#pragma unroll
        for (int fs = 0; fs < 4; ++fs) af[fs] = wsh[(c - 1) & 1][fs][L];
#pragma unroll
        for (int c2 = 0; c2 < 2; ++c2)
#pragma unroll
            for (int rc = 0; rc < 2; ++rc)
#pragma unroll
                for (int kb = 0; kb < 2; ++kb)
                    acc[c2][rc] = __builtin_amdgcn_mfma_f32_16x16x32_bf16(
                        af[rc * 2 + kb], Bbuf[c2][kb], acc[c2][rc], 0, 0, 0);

#pragma unroll
        for (int c2 = 0; c2 < 2; ++c2)
#pragma unroll
            for (int kb = 0; kb < 2; ++kb) Bbuf[c2][kb] = Bload[c2][kb];
    }

    // ---- epilogue: MFMA last chunk ----
    __syncthreads();
    {
        short8 af[4];
#pragma unroll
        for (int fs = 0; fs < 4; ++fs) af[fs] = wsh[(NC - 1) & 1][fs][L];
#pragma unroll
        for (int c2 = 0; c2 < 2; ++c2)
#pragma unroll
            for (int rc = 0; rc < 2; ++rc)
#pragma unroll
                for (int kb = 0; kb < 2; ++kb)
                    acc[c2][rc] = __builtin_amdgcn_mfma_f32_16x16x32_bf16(
                        af[rc * 2 + kb], Bbuf[c2][kb], acc[c2][rc], 0, 0, 0);
    }

    // store partials: D layout col=lane&15, row=quad*4+reg
    float* dst = split ? pacc + (size_t)(split - 1) * N * F : out;
#pragma unroll
    for (int c2 = 0; c2 < 2; ++c2) {
        const int col = (w * 2 + c2) * 16 + l16;
#pragma unroll
        for (int rc = 0; rc < 2; ++rc) {
            const int row0 = i0 + rc * 16 + quad * 4;
#pragma unroll
            for (int r = 0; r < 4; ++r)
                dst[(size_t)(row0 + r) * F + col] = acc[c2][rc][r];
        }
    }

    // row sums: butterfly over quads, then combine the two ks-waves via LDS
    rsum += __shfl_xor(rsum, 16);
    rsum += __shfl_xor(rsum, 32);
    if (L < 16) srow[rt][ks][l16] = rsum;
    __syncthreads();
    if (t < 32) pS[split * N + i0 + t] = srow[t >> 4][0][t & 15] + srow[t >> 4][1][t & 15];
}

// ---------------- K3: out = (out + pacc0 + pacc1 + pacc2) / (sum of 4 pS) ----------------
__global__ __launch_bounds__(256) void finalize(float* __restrict__ out,
                                                const float* __restrict__ pacc,
                                                const float* __restrict__ pS) {
    const int idx = (blockIdx.x * 256 + threadIdx.x) * 4;
    const int i = idx >> 7;
    const float inv = 1.0f / (pS[i] + pS[N + i] + pS[2 * N + i] + pS[3 * N + i]);
    float4 a0 = *(const float4*)&out[idx];
    float4 a1 = *(const float4*)&pacc[idx];
    float4 a2 = *(const float4*)&pacc[(size_t)N * F + idx];
    float4 a3 = *(const float4*)&pacc[2 * (size_t)N * F + idx];
    float4 o = {(a0.x + a1.x + a2.x + a3.x) * inv,
                (a0.y + a1.y + a2.y + a3.y) * inv,
                (a0.z + a1.z + a2.z + a3.z) * inv,
                (a0.w + a1.w + a2.w + a3.w) * inv};
    *(float4*)&out[idx] = o;
}

extern "C" void kernel_launch(void* const* d_in, const int* in_sizes, int n_in,
                              void* d_out, int out_size, void* d_ws, size_t ws_size,
                              hipStream_t stream) {
    (void)in_sizes; (void)n_in; (void)out_size; (void)ws_size;
    const float* x   = (const float*)d_in[0];
    const int*   adj = (const int*)d_in[1];
    const float* W   = (const float*)d_in[2];
    const float* a   = (const float*)d_in[3];
    float* out = (float*)d_out;

    u16* hT     = (u16*)d_ws;                    // N*F bf16 (2 MB)
    float* ssrc = (float*)(hT + (size_t)N * F);  // N
    float* sdst = ssrc + N;                      // N
    float* pS   = sdst + N;                      // NSPLIT*N
    float* pacc = pS + NSPLIT * N;               // (NSPLIT-1)*N*F fp32 (12 MB)

    gemm_h<<<N / 32, 256, 0, stream>>>(x, W, a, hT, ssrc, sdst);
    attn_mfma<<<dim3(N / 32, NSPLIT), 256, 0, stream>>>(adj, hT, ssrc, sdst, out, pacc, pS);
    finalize<<<(N * F / 4) / 256, 256, 0, stream>>>(out, pacc, pS);
}